// Round 2
// baseline (570.344 us; speedup 1.0000x reference)
//
#include <hip/hip_runtime.h>

// ConvLSTM1D fused scan for MI355X — f32 I/O, split-precision bf16 MFMA.
// B=32, T=50, S=2048, C=8, F=32, K=2, stride=2 -> sh=1024, 4F=128.
// Halo-tile trick: block owns j-range [j0, j0+64); recurrent conv reads h[j+1]
// only, so a right halo that starts at +49 rows and shrinks by 1 per step makes
// every block's 50-step scan fully independent (no grid sync).
// Precision: A and W split into bf16 hi+lo; z = Ah*Wh + Al*Wh + Ah*Wl (f32-acc
// MFMA) -> ~2^-16 relative matmul error. c-state f32 in registers.

#define TT 50
#define LTILE 64
#define ROWS 129   // 64 owned + 49 halo + 1 read-halo -> max row index read 128
#define HSTR 40    // h row stride (shorts); mult of 8 -> 16B-aligned ds_read_b128
#define WSTR 72    // rec-weight row stride (shorts)
#define XSTR 40    // x-weight row stride (shorts)

typedef __attribute__((ext_vector_type(8))) short short8;
typedef __attribute__((ext_vector_type(4))) float floatx4;

__device__ __forceinline__ float b2f_hi(unsigned short s) {
  union { float f; unsigned u; } v; v.u = ((unsigned)s) << 16; return v.f;
}
__device__ __forceinline__ unsigned short f2b_rne(float f) {
  union { float f; unsigned u; } v; v.f = f;
  unsigned r = v.u + 0x7FFFu + ((v.u >> 16) & 1u);
  return (unsigned short)(r >> 16);
}
__device__ __forceinline__ unsigned short f2b_trunc(float f) {
  union { float f; unsigned u; } v; v.f = f;
  return (unsigned short)(v.u >> 16);
}
__device__ __forceinline__ float trunc_rem(float f) {
  union { float f; unsigned u; } v; v.f = f;
  v.u &= 0xFFFF0000u;
  return f - v.f;   // exact: low mantissa bits of f
}
__device__ __forceinline__ float hsig(float x) {
  float y = __builtin_fmaf(0.2f, x, 0.5f);
  return fminf(fmaxf(y, 0.0f), 1.0f);
}
__device__ __forceinline__ float ftanh(float x) {
  // tanh(x) = 1 - 2/(exp(2x)+1); overflow/underflow saturate to +-1 gracefully.
  float e = __expf(2.0f * x);
  return 1.0f - 2.0f * __builtin_amdgcn_rcpf(e + 1.0f);
}

__global__ __launch_bounds__(256, 1)
void convlstm_scan(const float* __restrict__ xs,   // x [32][50][2048][8] f32
                   const float* __restrict__ ks,   // kernel [2][8][128] f32
                   const float* __restrict__ rks,  // rec_kernel [2][32][128] f32
                   const float* __restrict__ bs,   // bias [128] f32
                   const float* __restrict__ dws,  // dense_w [32768] f32
                   float* __restrict__ acc_out) {  // [32] f32 accumulators
  __shared__ short hbH[2][ROWS * HSTR];   // h hi (bf16), double-buffered
  __shared__ short hbL[2][ROWS * HSTR];   // h lo (bf16)
  __shared__ short WhiT[128 * WSTR];      // rec W hi, transposed [oc][k0..63]
  __shared__ short WloT[128 * WSTR];      // rec W lo
  __shared__ short XwT[128 * XSTR];       // [k_hi(16); k_hi(16)] transposed
  __shared__ short XlT[128 * XSTR];       // [k_lo(16); 0(16)] transposed

  const int tid  = threadIdx.x;
  const int b    = blockIdx.x >> 4;
  const int j0   = (blockIdx.x & 15) * LTILE;
  const int wave = tid >> 6;
  const int lane = tid & 63;
  const int q    = lane >> 4;
  const int f0   = lane & 15;

  // ---- stage weights (f32 -> bf16 hi/lo split), transposed for B-frag reads
  for (int e = tid; e < 64 * 128; e += 256) {
    int k = e >> 7, oc = e & 127;        // e == k*128 + oc, k = tap*32 + c
    float w = rks[e];
    unsigned short hi = f2b_rne(w);
    unsigned short lo = f2b_rne(w - b2f_hi(hi));
    WhiT[oc * WSTR + k] = (short)hi;
    WloT[oc * WSTR + k] = (short)lo;
  }
  for (int e = tid; e < 16 * 128; e += 256) {
    int kk = e >> 7, oc = e & 127;       // kk = tap*8 + c
    float w = ks[e];
    unsigned short hi = f2b_rne(w);
    unsigned short lo = f2b_rne(w - b2f_hi(hi));
    XwT[oc * XSTR + kk]      = (short)hi;
    XwT[oc * XSTR + 16 + kk] = (short)hi;   // [k_hi; k_hi] for [x_hi|x_lo] A
    XlT[oc * XSTR + kk]      = (short)lo;
    XlT[oc * XSTR + 16 + kk] = 0;           // upper half zero -> A is don't-care
  }
  for (int e = tid; e < 2 * ROWS * HSTR; e += 256) {
    ((short*)hbH)[e] = 0;
    ((short*)hbL)[e] = 0;
  }
  __syncthreads();

  // ---- B fragments resident in registers for the whole kernel (192 VGPR)
  // B[k=q*8+j][n-col=f0] per lane (symmetric to verified A layout).
  short8 Bwh0[8], Bwh1[8], Bwl0[8], Bwl1[8], Bxw[8], Bxl[8];
#pragma unroll
  for (int n = 0; n < 8; ++n) {
    int r = n * 16 + f0;
    Bwh0[n] = *(const short8*)&WhiT[r * WSTR + q * 8];
    Bwh1[n] = *(const short8*)&WhiT[r * WSTR + 32 + q * 8];
    Bwl0[n] = *(const short8*)&WloT[r * WSTR + q * 8];
    Bwl1[n] = *(const short8*)&WloT[r * WSTR + 32 + q * 8];
    Bxw[n]  = *(const short8*)&XwT[r * XSTR + q * 8];
    Bxl[n]  = *(const short8*)&XlT[r * XSTR + q * 8];
  }

  float bias_v[8];
#pragma unroll
  for (int n = 0; n < 8; ++n) bias_v[n] = bs[n * 16 + f0];

  float cst[2][8];   // c-state, MFMA C-layout: [m-slot][p*4 + r]
#pragma unroll
  for (int s = 0; s < 2; ++s)
#pragma unroll
    for (int i = 0; i < 8; ++i) cst[s][i] = 0.0f;

  const int maxrows = 1024 - j0;

  for (int t = 0; t < TT; ++t) {
    const short* curH = hbH[t & 1];
    const short* curL = hbL[t & 1];
    short* nxtH = hbH[(t & 1) ^ 1];
    short* nxtL = hbL[(t & 1) ^ 1];
    int rows = LTILE + (TT - 1) - t;
    if (rows > maxrows) rows = maxrows;
    const int nmt = (rows + 15) >> 4;
    const float* xrow = xs + (size_t)(b * TT + t) * (2048 * 8);

    for (int m = wave; m < nmt; m += 4) {
      const int slot = m >> 2;
      const int jr = m * 16 + f0;          // A row = lane&15
      // A fragments from LDS: rec part k 0..31 = h[jr], 32..63 = h[jr+1]
      short8 a0h = *(const short8*)&curH[jr * HSTR + q * 8];
      short8 a0l = *(const short8*)&curL[jr * HSTR + q * 8];
      short8 a1h = *(const short8*)&curH[(jr + 1) * HSTR + q * 8];
      short8 a1l = *(const short8*)&curL[(jr + 1) * HSTR + q * 8];
      // x fragment from global f32, split on the fly.
      // k = q*8+j: q0 -> hi(x[2J][j]), q1 -> hi(x[2J+1][j]),
      //            q2 -> lo(x[2J][j]), q3 -> lo(x[2J+1][j])
      const float* xp = xrow + ((size_t)(2 * (j0 + jr) + (q & 1)) * 8);
      floatx4 x0 = *(const floatx4*)xp;
      floatx4 x1 = *(const floatx4*)(xp + 4);
      short8 ax;
      if (q < 2) {
#pragma unroll
        for (int jj = 0; jj < 4; ++jj) ax[jj] = (short)f2b_trunc(x0[jj]);
#pragma unroll
        for (int jj = 0; jj < 4; ++jj) ax[4 + jj] = (short)f2b_trunc(x1[jj]);
      } else {
#pragma unroll
        for (int jj = 0; jj < 4; ++jj) ax[jj] = (short)f2b_rne(trunc_rem(x0[jj]));
#pragma unroll
        for (int jj = 0; jj < 4; ++jj) ax[4 + jj] = (short)f2b_rne(trunc_rem(x1[jj]));
      }

      floatx4 acc[8];
#pragma unroll
      for (int n = 0; n < 8; ++n) {
        float bv = bias_v[n];
        floatx4 a; a[0] = bv; a[1] = bv; a[2] = bv; a[3] = bv;
        acc[n] = a;
      }
      // z = Ah*Wh + Al*Wh + Ah*Wl + x-part  (8 k-blocks, n-inner for ILP)
#pragma unroll
      for (int n = 0; n < 8; ++n)
        acc[n] = __builtin_amdgcn_mfma_f32_16x16x32_bf16(a0h, Bwh0[n], acc[n], 0, 0, 0);
#pragma unroll
      for (int n = 0; n < 8; ++n)
        acc[n] = __builtin_amdgcn_mfma_f32_16x16x32_bf16(a1h, Bwh1[n], acc[n], 0, 0, 0);
#pragma unroll
      for (int n = 0; n < 8; ++n)
        acc[n] = __builtin_amdgcn_mfma_f32_16x16x32_bf16(a0l, Bwh0[n], acc[n], 0, 0, 0);
#pragma unroll
      for (int n = 0; n < 8; ++n)
        acc[n] = __builtin_amdgcn_mfma_f32_16x16x32_bf16(a1l, Bwh1[n], acc[n], 0, 0, 0);
#pragma unroll
      for (int n = 0; n < 8; ++n)
        acc[n] = __builtin_amdgcn_mfma_f32_16x16x32_bf16(a0h, Bwl0[n], acc[n], 0, 0, 0);
#pragma unroll
      for (int n = 0; n < 8; ++n)
        acc[n] = __builtin_amdgcn_mfma_f32_16x16x32_bf16(a1h, Bwl1[n], acc[n], 0, 0, 0);
#pragma unroll
      for (int n = 0; n < 8; ++n)
        acc[n] = __builtin_amdgcn_mfma_f32_16x16x32_bf16(ax, Bxw[n], acc[n], 0, 0, 0);
#pragma unroll
      for (int n = 0; n < 8; ++n)
        acc[n] = __builtin_amdgcn_mfma_f32_16x16x32_bf16(ax, Bxl[n], acc[n], 0, 0, 0);

      // Pointwise LSTM. D[m-row = q*4+r][oc-col = n*16+f0].
      // Gates: oc 0..31 = i, 32..63 = f, 64..95 = c, 96..127 = o.
      const int jw = m * 16 + q * 4;
#pragma unroll
      for (int p = 0; p < 2; ++p) {
#pragma unroll
        for (int r = 0; r < 4; ++r) {
          float zi = acc[0 + p][r], zf = acc[2 + p][r];
          float zc = acc[4 + p][r], zo = acc[6 + p][r];
          float ig = hsig(zi), fg = hsig(zf), og = hsig(zo);
          float cs = cst[slot][p * 4 + r];
          float cn = __builtin_fmaf(fg, cs, ig * ftanh(zc));
          cst[slot][p * 4 + r] = cn;
          float hv = og * ftanh(cn);
          unsigned short hh = f2b_trunc(hv);
          float rem = trunc_rem(hv);
          nxtH[(jw + r) * HSTR + p * 16 + f0] = (short)hh;
          nxtL[(jw + r) * HSTR + p * 16 + f0] = (short)f2b_rne(rem);
        }
      }
    }
    __syncthreads();
  }

  // ---- Dense(1) epilogue: final h in buffer 0 (t=49 wrote hb[0]).
  const short* hH = hbH[0];
  const short* hL = hbL[0];
  float part = 0.0f;
  for (int e = tid; e < LTILE * 32; e += 256) {
    int jr = e >> 5, f = e & 31;
    float hv = b2f_hi((unsigned short)hH[jr * HSTR + f]) +
               b2f_hi((unsigned short)hL[jr * HSTR + f]);
    part += hv * dws[(j0 + jr) * 32 + f];
  }
#pragma unroll
  for (int off = 32; off > 0; off >>= 1) part += __shfl_down(part, off);
  if (lane == 0) atomicAdd(&acc_out[b], part);
}

__global__ void init_acc(float* ws) {
  if (threadIdx.x < 32) ws[threadIdx.x] = 0.0f;
}

__global__ void finalize(const float* __restrict__ ws,
                         const float* __restrict__ db,
                         float* __restrict__ out) {
  int i = threadIdx.x;
  if (i < 32) out[i] = ws[i] + db[0];
}

extern "C" void kernel_launch(void* const* d_in, const int* in_sizes, int n_in,
                              void* d_out, int out_size, void* d_ws, size_t ws_size,
                              hipStream_t stream) {
  const float* x  = (const float*)d_in[0];
  const float* k  = (const float*)d_in[1];
  const float* rk = (const float*)d_in[2];
  const float* bi = (const float*)d_in[3];
  const float* dw = (const float*)d_in[4];
  const float* db = (const float*)d_in[5];
  float* ws = (float*)d_ws;
  float* out = (float*)d_out;

  hipLaunchKernelGGL(init_acc, dim3(1), dim3(64), 0, stream, ws);
  hipLaunchKernelGGL(convlstm_scan, dim3(512), dim3(256), 0, stream,
                     x, k, rk, bi, dw, ws);
  hipLaunchKernelGGL(finalize, dim3(1), dim3(64), 0, stream, ws, db, out);
}

// Round 3
// 365.448 us; speedup vs baseline: 1.5607x; 1.5607x over previous
//
#include <hip/hip_runtime.h>

// ConvLSTM1D fused scan for MI355X — f32 I/O, split-precision bf16 MFMA.
// Round 3: no weight LDS (B-frags gathered from global into registers),
// 2 blocks/CU, x software-pipelined into VGPRs.
// Halo-tile trick: block owns j-range [j0, j0+64); recurrent conv reads h[j+1]
// only, so a right halo that starts at +49 rows and shrinks by 1 per step makes
// every block's 50-step scan fully independent (no grid sync).
// Precision: z = Ah*Wh + Al*Wh + Ah*Wl + [xh|xl]*[kh;kh]  (f32-acc MFMA);
// only xh*kl and lo*lo terms dropped. c-state f32 in registers.

#define TT 50
#define LTILE 64
#define ROWS 129   // 64 owned + 49 halo + 1 read-halo row
#define HSTR 40    // h row stride (shorts); mult of 8 -> 16B-aligned ds_read_b128

typedef __attribute__((ext_vector_type(8))) short short8;
typedef __attribute__((ext_vector_type(4))) float floatx4;

__device__ __forceinline__ float b2f_hi(unsigned short s) {
  union { float f; unsigned u; } v; v.u = ((unsigned)s) << 16; return v.f;
}
__device__ __forceinline__ unsigned short f2b_rne(float f) {
  union { float f; unsigned u; } v; v.f = f;
  unsigned r = v.u + 0x7FFFu + ((v.u >> 16) & 1u);
  return (unsigned short)(r >> 16);
}
__device__ __forceinline__ unsigned short f2b_trunc(float f) {
  union { float f; unsigned u; } v; v.f = f;
  return (unsigned short)(v.u >> 16);
}
__device__ __forceinline__ float trunc_rem(float f) {
  union { float f; unsigned u; } v; v.f = f;
  v.u &= 0xFFFF0000u;
  return f - v.f;   // exact
}
__device__ __forceinline__ float hsig(float x) {
  float y = __builtin_fmaf(0.2f, x, 0.5f);
  return fminf(fmaxf(y, 0.0f), 1.0f);
}
__device__ __forceinline__ float ftanh(float x) {
  float e = __expf(2.0f * x);
  return 1.0f - 2.0f * __builtin_amdgcn_rcpf(e + 1.0f);
}

__global__ __launch_bounds__(256, 2)
void convlstm_scan(const float* __restrict__ xs,   // x [32][50][2048][8] f32
                   const float* __restrict__ ks,   // kernel [2][8][128] f32
                   const float* __restrict__ rks,  // rec_kernel [2][32][128] f32
                   const float* __restrict__ bs,   // bias [128] f32
                   const float* __restrict__ dws,  // dense_w [32768] f32
                   float* __restrict__ acc_out) {  // [32] f32 accumulators
  __shared__ short hbH[2][ROWS * HSTR];   // h hi (bf16), double-buffered
  __shared__ short hbL[2][ROWS * HSTR];   // h lo (bf16)

  const int tid  = threadIdx.x;
  const int b    = blockIdx.x >> 4;
  const int j0   = (blockIdx.x & 15) * LTILE;
  const int wave = tid >> 6;
  const int lane = tid & 63;
  const int q    = lane >> 4;
  const int f0   = lane & 15;

  // zero h state (ints: 2*ROWS*HSTR shorts == ROWS*HSTR ints per array)
  for (int e = tid; e < ROWS * HSTR; e += 256) {
    ((int*)hbH)[e] = 0;
    ((int*)hbL)[e] = 0;
  }

  // ---- B fragments gathered straight into registers (no LDS round trip).
  // B[k = q*8+j][oc-col = n*16+f0] per lane. rec_kernel[k][oc], k = tap*32+c.
  short8 Bwh0[8], Bwl0[8], Bwh1[8], Bwl1[8], Bxw[8];
#pragma unroll
  for (int n = 0; n < 8; ++n) {
    const int oc = n * 16 + f0;
    short8 th, tl;
#pragma unroll
    for (int j = 0; j < 8; ++j) {
      float w = rks[(q * 8 + j) * 128 + oc];
      unsigned short hi = f2b_rne(w);
      th[j] = (short)hi;
      tl[j] = (short)f2b_rne(w - b2f_hi(hi));
    }
    Bwh0[n] = th; Bwl0[n] = tl;
#pragma unroll
    for (int j = 0; j < 8; ++j) {
      float w = rks[(32 + q * 8 + j) * 128 + oc];
      unsigned short hi = f2b_rne(w);
      th[j] = (short)hi;
      tl[j] = (short)f2b_rne(w - b2f_hi(hi));
    }
    Bwh1[n] = th; Bwl1[n] = tl;
    // x-conv weights: rows 0..15 = k_hi, rows 16..31 duplicate k_hi
    // (pairs with A = [x_hi | x_lo] to capture (xh+xl)*kh in one MFMA).
    short8 tx;
#pragma unroll
    for (int j = 0; j < 8; ++j) {
      float w = ks[((q & 1) * 8 + j) * 128 + oc];
      tx[j] = (short)f2b_rne(w);
    }
    Bxw[n] = tx;
  }

  float bias_v[8];
#pragma unroll
  for (int n = 0; n < 8; ++n) bias_v[n] = bs[n * 16 + f0];

  float cst[2][8];   // c-state, MFMA C-layout: [m-slot][p*4 + r]
#pragma unroll
  for (int s = 0; s < 2; ++s)
#pragma unroll
    for (int i = 0; i < 8; ++i) cst[s][i] = 0.0f;

  // ---- initial x prefetch (t=0) for both slots
  floatx4 px0[2], px1[2];
#pragma unroll
  for (int s = 0; s < 2; ++s) {
    const int jr = (wave + 4 * s) * 16 + f0;
    const int jm = min(j0 + jr, 1023);
    const float* xp = xs + (size_t)b * TT * (2048 * 8) +
                      (size_t)(2 * jm + (q & 1)) * 8;
    px0[s] = *(const floatx4*)xp;
    px1[s] = *(const floatx4*)(xp + 4);
  }

  const int maxrows = 1024 - j0;
  __syncthreads();

  for (int t = 0; t < TT; ++t) {
    const short* curH = hbH[t & 1];
    const short* curL = hbL[t & 1];
    short* nxtH = hbH[(t & 1) ^ 1];
    short* nxtL = hbL[(t & 1) ^ 1];
    int rows = LTILE + (TT - 1) - t;          // halo shrinks 1/step
    if (rows > maxrows) rows = maxrows;
    const int nmt = (rows + 15) >> 4;
    const int tn = (t < TT - 1) ? t + 1 : t;  // clamped prefetch time
    const float* xnext = xs + ((size_t)(b * TT + tn)) * (2048 * 8);

#pragma unroll
    for (int s = 0; s < 2; ++s) {
      const int m = wave + 4 * s;             // wave-uniform
      if (m >= nmt) continue;
      const int jr = m * 16 + f0;             // A row = lane&15

      // A fragments from LDS: k 0..31 = h[jr], 32..63 = h[jr+1]
      short8 a0h = *(const short8*)&curH[jr * HSTR + q * 8];
      short8 a0l = *(const short8*)&curL[jr * HSTR + q * 8];
      short8 a1h = *(const short8*)&curH[(jr + 1) * HSTR + q * 8];
      short8 a1l = *(const short8*)&curL[(jr + 1) * HSTR + q * 8];

      // x fragment from the prefetched registers; split hi/lo on the fly.
      // k = q*8+j: q0 -> hi(x[2J]), q1 -> hi(x[2J+1]), q2 -> lo(x[2J]),
      // q3 -> lo(x[2J+1]).
      floatx4 x0 = px0[s], x1 = px1[s];
      short8 ax;
      if (q < 2) {
#pragma unroll
        for (int jj = 0; jj < 4; ++jj) ax[jj] = (short)f2b_trunc(x0[jj]);
#pragma unroll
        for (int jj = 0; jj < 4; ++jj) ax[4 + jj] = (short)f2b_trunc(x1[jj]);
      } else {
#pragma unroll
        for (int jj = 0; jj < 4; ++jj) ax[jj] = (short)f2b_rne(trunc_rem(x0[jj]));
#pragma unroll
        for (int jj = 0; jj < 4; ++jj) ax[4 + jj] = (short)f2b_rne(trunc_rem(x1[jj]));
      }

      // prefetch this slot's x for t+1 (overlaps MFMA + pointwise below)
      {
        const int jm = min(j0 + jr, 1023);
        const float* xp = xnext + (size_t)(2 * jm + (q & 1)) * 8;
        px0[s] = *(const floatx4*)xp;
        px1[s] = *(const floatx4*)(xp + 4);
      }

      floatx4 acc[8];
#pragma unroll
      for (int n = 0; n < 8; ++n) {
        float bv = bias_v[n];
        floatx4 a; a[0] = bv; a[1] = bv; a[2] = bv; a[3] = bv;
        acc[n] = a;
      }
#pragma unroll
      for (int n = 0; n < 8; ++n)
        acc[n] = __builtin_amdgcn_mfma_f32_16x16x32_bf16(a0h, Bwh0[n], acc[n], 0, 0, 0);
#pragma unroll
      for (int n = 0; n < 8; ++n)
        acc[n] = __builtin_amdgcn_mfma_f32_16x16x32_bf16(a1h, Bwh1[n], acc[n], 0, 0, 0);
#pragma unroll
      for (int n = 0; n < 8; ++n)
        acc[n] = __builtin_amdgcn_mfma_f32_16x16x32_bf16(a0l, Bwh0[n], acc[n], 0, 0, 0);
#pragma unroll
      for (int n = 0; n < 8; ++n)
        acc[n] = __builtin_amdgcn_mfma_f32_16x16x32_bf16(a1l, Bwh1[n], acc[n], 0, 0, 0);
#pragma unroll
      for (int n = 0; n < 8; ++n)
        acc[n] = __builtin_amdgcn_mfma_f32_16x16x32_bf16(a0h, Bwl0[n], acc[n], 0, 0, 0);
#pragma unroll
      for (int n = 0; n < 8; ++n)
        acc[n] = __builtin_amdgcn_mfma_f32_16x16x32_bf16(a1h, Bwl1[n], acc[n], 0, 0, 0);
#pragma unroll
      for (int n = 0; n < 8; ++n)
        acc[n] = __builtin_amdgcn_mfma_f32_16x16x32_bf16(ax, Bxw[n], acc[n], 0, 0, 0);

      // Pointwise LSTM. D[m-row = q*4+r][oc-col = n*16+f0].
      // Gates: oc 0..31 = i, 32..63 = f, 64..95 = c, 96..127 = o.
      const int jw = m * 16 + q * 4;
#pragma unroll
      for (int p = 0; p < 2; ++p) {
#pragma unroll
        for (int r = 0; r < 4; ++r) {
          float zi = acc[0 + p][r], zf = acc[2 + p][r];
          float zc = acc[4 + p][r], zo = acc[6 + p][r];
          float ig = hsig(zi), fg = hsig(zf), og = hsig(zo);
          float cs = cst[s][p * 4 + r];
          float cn = __builtin_fmaf(fg, cs, ig * ftanh(zc));
          cst[s][p * 4 + r] = cn;
          float hv = og * ftanh(cn);
          unsigned short hh = f2b_trunc(hv);
          float rem = trunc_rem(hv);
          nxtH[(jw + r) * HSTR + p * 16 + f0] = (short)hh;
          nxtL[(jw + r) * HSTR + p * 16 + f0] = (short)f2b_rne(rem);
        }
      }
    }
    __syncthreads();
  }

  // ---- Dense(1) epilogue: final h in buffer 0 (TT even).
  const short* hH = hbH[0];
  const short* hL = hbL[0];
  float part = 0.0f;
  for (int e = tid; e < LTILE * 32; e += 256) {
    int jr = e >> 5, f = e & 31;
    float hv = b2f_hi((unsigned short)hH[jr * HSTR + f]) +
               b2f_hi((unsigned short)hL[jr * HSTR + f]);
    part += hv * dws[(j0 + jr) * 32 + f];
  }
#pragma unroll
  for (int off = 32; off > 0; off >>= 1) part += __shfl_down(part, off);
  if (lane == 0) atomicAdd(&acc_out[b], part);
}

__global__ void init_acc(float* ws) {
  if (threadIdx.x < 32) ws[threadIdx.x] = 0.0f;
}

__global__ void finalize(const float* __restrict__ ws,
                         const float* __restrict__ db,
                         float* __restrict__ out) {
  int i = threadIdx.x;
  if (i < 32) out[i] = ws[i] + db[0];
}

extern "C" void kernel_launch(void* const* d_in, const int* in_sizes, int n_in,
                              void* d_out, int out_size, void* d_ws, size_t ws_size,
                              hipStream_t stream) {
  const float* x  = (const float*)d_in[0];
  const float* k  = (const float*)d_in[1];
  const float* rk = (const float*)d_in[2];
  const float* bi = (const float*)d_in[3];
  const float* dw = (const float*)d_in[4];
  const float* db = (const float*)d_in[5];
  float* ws = (float*)d_ws;
  float* out = (float*)d_out;

  hipLaunchKernelGGL(init_acc, dim3(1), dim3(64), 0, stream, ws);
  hipLaunchKernelGGL(convlstm_scan, dim3(512), dim3(256), 0, stream,
                     x, k, rk, bi, dw, ws);
  hipLaunchKernelGGL(finalize, dim3(1), dim3(64), 0, stream, ws, db, out);
}

// Round 4
// 266.458 us; speedup vs baseline: 2.1405x; 1.3715x over previous
//
#include <hip/hip_runtime.h>

// ConvLSTM1D fused scan for MI355X — f32 I/O, split-precision bf16 MFMA.
// Round 4: fit the register budget (no spills). B-frags trimmed to 96 VGPR by
// dropping the Ah*Wl correction (weights bf16-rne; A=h stays hi+lo split).
// z = (Ah + Al)*Wh + [xh|xl]*[kh;kh] + bias  -> 5 MFMA k-blocks x 8 n-tiles.
// Halo-tile trick: block owns j-range [j0, j0+64); recurrent conv reads h[j+1]
// only, so a right halo that starts at +49 rows and shrinks by 1 per step makes
// every block's 50-step scan fully independent (no grid sync).

#define TT 50
#define LTILE 64
#define ROWS 129   // 64 owned + 49 halo + 1 read-halo row (row 128 stays 0)
#define HSTR 40    // h row stride (shorts); mult of 8 -> 16B-aligned ds_read_b128

typedef __attribute__((ext_vector_type(8))) short short8;
typedef __attribute__((ext_vector_type(4))) float floatx4;

__device__ __forceinline__ float b2f_hi(unsigned short s) {
  union { float f; unsigned u; } v; v.u = ((unsigned)s) << 16; return v.f;
}
__device__ __forceinline__ unsigned short f2b_rne(float f) {
  union { float f; unsigned u; } v; v.f = f;
  unsigned r = v.u + 0x7FFFu + ((v.u >> 16) & 1u);
  return (unsigned short)(r >> 16);
}
__device__ __forceinline__ unsigned short f2b_trunc(float f) {
  union { float f; unsigned u; } v; v.f = f;
  return (unsigned short)(v.u >> 16);
}
__device__ __forceinline__ float trunc_rem(float f) {
  union { float f; unsigned u; } v; v.f = f;
  v.u &= 0xFFFF0000u;
  return f - v.f;   // exact
}
__device__ __forceinline__ float hsig(float x) {
  float y = __builtin_fmaf(0.2f, x, 0.5f);
  return fminf(fmaxf(y, 0.0f), 1.0f);
}
__device__ __forceinline__ float ftanh(float x) {
  float e = __expf(2.0f * x);
  return 1.0f - 2.0f * __builtin_amdgcn_rcpf(e + 1.0f);
}

__global__ __launch_bounds__(256, 2)
void convlstm_scan(const float* __restrict__ xs,   // x [32][50][2048][8] f32
                   const float* __restrict__ ks,   // kernel [2][8][128] f32
                   const float* __restrict__ rks,  // rec_kernel [2][32][128] f32
                   const float* __restrict__ bs,   // bias [128] f32
                   const float* __restrict__ dws,  // dense_w [32768] f32
                   float* __restrict__ acc_out) {  // [32] f32 accumulators
  __shared__ short hbH[2][ROWS * HSTR];   // h hi (bf16), double-buffered
  __shared__ short hbL[2][ROWS * HSTR];   // h lo (bf16)

  const int tid  = threadIdx.x;
  const int b    = blockIdx.x >> 4;
  const int j0   = (blockIdx.x & 15) * LTILE;
  const int wave = tid >> 6;
  const int lane = tid & 63;
  const int q    = lane >> 4;
  const int f0   = lane & 15;

  for (int e = tid; e < ROWS * HSTR; e += 256) {
    ((int*)hbH)[e] = 0;
    ((int*)hbL)[e] = 0;
  }

  // ---- B fragments gathered straight into registers (96 VGPR total).
  // B[k = q*8+j][oc-col = n*16+f0] per lane. rec_kernel[k][oc], k = tap*32+c.
  short8 Bwh0[8], Bwh1[8], Bxw[8];
#pragma unroll
  for (int n = 0; n < 8; ++n) {
    const int oc = n * 16 + f0;
    short8 th;
#pragma unroll
    for (int j = 0; j < 8; ++j)
      th[j] = (short)f2b_rne(rks[(q * 8 + j) * 128 + oc]);
    Bwh0[n] = th;
#pragma unroll
    for (int j = 0; j < 8; ++j)
      th[j] = (short)f2b_rne(rks[(32 + q * 8 + j) * 128 + oc]);
    Bwh1[n] = th;
    // x-conv weights: k rows 0..15 = k_hi, rows 16..31 duplicate k_hi
    // (pairs with A = [x_hi | x_lo] to capture (xh+xl)*kh in one MFMA).
    short8 tx;
#pragma unroll
    for (int j = 0; j < 8; ++j)
      tx[j] = (short)f2b_rne(ks[((q & 1) * 8 + j) * 128 + oc]);
    Bxw[n] = tx;
  }

  float bias_v[8];
#pragma unroll
  for (int n = 0; n < 8; ++n) bias_v[n] = bs[n * 16 + f0];

  float cst[2][8];   // c-state, MFMA C-layout: [m-slot][p*4 + r]
#pragma unroll
  for (int s = 0; s < 2; ++s)
#pragma unroll
    for (int i = 0; i < 8; ++i) cst[s][i] = 0.0f;

  // ---- initial x prefetch (t=0) for both slots
  floatx4 px0[2], px1[2];
#pragma unroll
  for (int s = 0; s < 2; ++s) {
    const int jr = (wave + 4 * s) * 16 + f0;
    const int jm = min(j0 + jr, 1023);
    const float* xp = xs + (size_t)b * TT * (2048 * 8) +
                      (size_t)(2 * jm + (q & 1)) * 8;
    px0[s] = *(const floatx4*)xp;
    px1[s] = *(const floatx4*)(xp + 4);
  }

  const int maxrows = 1024 - j0;
  __syncthreads();

  for (int t = 0; t < TT; ++t) {
    const short* curH = hbH[t & 1];
    const short* curL = hbL[t & 1];
    short* nxtH = hbH[(t & 1) ^ 1];
    short* nxtL = hbL[(t & 1) ^ 1];
    int rows = LTILE + (TT - 1) - t;          // halo shrinks 1/step
    if (rows > maxrows) rows = maxrows;
    const int nmt = (rows + 15) >> 4;         // 4..8; slot0 (m=wave) always live
    const int act1 = (wave + 4) < nmt;        // wave-uniform slot1 guard
    const int tn = (t < TT - 1) ? t + 1 : t;
    const float* xnext = xs + ((size_t)(b * TT + tn)) * (2048 * 8);

    // 1) Build ax for both slots from the registers prefetched last step.
    // k = q*8+j: q0 -> hi(x[2J]), q1 -> hi(x[2J+1]), q2 -> lo(x[2J]),
    // q3 -> lo(x[2J+1]).
    short8 ax[2];
#pragma unroll
    for (int s = 0; s < 2; ++s) {
      floatx4 x0 = px0[s], x1 = px1[s];
      if (q < 2) {
#pragma unroll
        for (int jj = 0; jj < 4; ++jj) ax[s][jj] = (short)f2b_trunc(x0[jj]);
#pragma unroll
        for (int jj = 0; jj < 4; ++jj) ax[s][4 + jj] = (short)f2b_trunc(x1[jj]);
      } else {
#pragma unroll
        for (int jj = 0; jj < 4; ++jj) ax[s][jj] = (short)f2b_rne(trunc_rem(x0[jj]));
#pragma unroll
        for (int jj = 0; jj < 4; ++jj) ax[s][4 + jj] = (short)f2b_rne(trunc_rem(x1[jj]));
      }
    }

    // 2) Issue next-step x prefetch immediately (longest latency first).
#pragma unroll
    for (int s = 0; s < 2; ++s) {
      const int jr = (wave + 4 * s) * 16 + f0;
      const int jm = min(j0 + jr, 1023);
      const float* xp = xnext + (size_t)(2 * jm + (q & 1)) * 8;
      px0[s] = *(const floatx4*)xp;
      px1[s] = *(const floatx4*)(xp + 4);
    }

    // 3) Front-load ALL a-frag LDS reads (both slots; always in-bounds:
    //    max row read = 7*16+15+1 = 128 = ROWS-1).
    short8 a0h[2], a0l[2], a1h[2], a1l[2];
#pragma unroll
    for (int s = 0; s < 2; ++s) {
      const int jr = (wave + 4 * s) * 16 + f0;
      a0h[s] = *(const short8*)&curH[jr * HSTR + q * 8];
      a0l[s] = *(const short8*)&curL[jr * HSTR + q * 8];
      a1h[s] = *(const short8*)&curH[(jr + 1) * HSTR + q * 8];
      a1l[s] = *(const short8*)&curL[(jr + 1) * HSTR + q * 8];
    }

    // 4) Per-slot MFMA + pointwise.
#pragma unroll
    for (int s = 0; s < 2; ++s) {
      if (s == 1 && !act1) continue;
      const int m = wave + 4 * s;

      floatx4 acc[8];
#pragma unroll
      for (int n = 0; n < 8; ++n) {
        float bv = bias_v[n];
        floatx4 a; a[0] = bv; a[1] = bv; a[2] = bv; a[3] = bv;
        acc[n] = a;
      }
      // ax first: operands already in registers, issues while ds_reads land.
#pragma unroll
      for (int n = 0; n < 8; ++n)
        acc[n] = __builtin_amdgcn_mfma_f32_16x16x32_bf16(ax[s], Bxw[n], acc[n], 0, 0, 0);
#pragma unroll
      for (int n = 0; n < 8; ++n)
        acc[n] = __builtin_amdgcn_mfma_f32_16x16x32_bf16(a0h[s], Bwh0[n], acc[n], 0, 0, 0);
#pragma unroll
      for (int n = 0; n < 8; ++n)
        acc[n] = __builtin_amdgcn_mfma_f32_16x16x32_bf16(a1h[s], Bwh1[n], acc[n], 0, 0, 0);
#pragma unroll
      for (int n = 0; n < 8; ++n)
        acc[n] = __builtin_amdgcn_mfma_f32_16x16x32_bf16(a0l[s], Bwh0[n], acc[n], 0, 0, 0);
#pragma unroll
      for (int n = 0; n < 8; ++n)
        acc[n] = __builtin_amdgcn_mfma_f32_16x16x32_bf16(a1l[s], Bwh1[n], acc[n], 0, 0, 0);

      // Pointwise LSTM. D[m-row = q*4+r][oc-col = n*16+f0].
      // Gates: oc 0..31 = i, 32..63 = f, 64..95 = c, 96..127 = o.
      const int jw = m * 16 + q * 4;
#pragma unroll
      for (int p = 0; p < 2; ++p) {
#pragma unroll
        for (int r = 0; r < 4; ++r) {
          float zi = acc[0 + p][r], zf = acc[2 + p][r];
          float zc = acc[4 + p][r], zo = acc[6 + p][r];
          float ig = hsig(zi), fg = hsig(zf), og = hsig(zo);
          float cs = cst[s][p * 4 + r];
          float cn = __builtin_fmaf(fg, cs, ig * ftanh(zc));
          cst[s][p * 4 + r] = cn;
          float hv = og * ftanh(cn);
          unsigned short hh = f2b_trunc(hv);
          float rem = trunc_rem(hv);
          nxtH[(jw + r) * HSTR + p * 16 + f0] = (short)hh;
          nxtL[(jw + r) * HSTR + p * 16 + f0] = (short)f2b_rne(rem);
        }
      }
    }
    __syncthreads();
  }

  // ---- Dense(1) epilogue: final h in buffer 0 (TT even).
  const short* hH = hbH[0];
  const short* hL = hbL[0];
  float part = 0.0f;
  for (int e = tid; e < LTILE * 32; e += 256) {
    int jr = e >> 5, f = e & 31;
    float hv = b2f_hi((unsigned short)hH[jr * HSTR + f]) +
               b2f_hi((unsigned short)hL[jr * HSTR + f]);
    part += hv * dws[(j0 + jr) * 32 + f];
  }
#pragma unroll
  for (int off = 32; off > 0; off >>= 1) part += __shfl_down(part, off);
  if (lane == 0) atomicAdd(&acc_out[b], part);
}

__global__ void init_acc(float* ws) {
  if (threadIdx.x < 32) ws[threadIdx.x] = 0.0f;
}

__global__ void finalize(const float* __restrict__ ws,
                         const float* __restrict__ db,
                         float* __restrict__ out) {
  int i = threadIdx.x;
  if (i < 32) out[i] = ws[i] + db[0];
}

extern "C" void kernel_launch(void* const* d_in, const int* in_sizes, int n_in,
                              void* d_out, int out_size, void* d_ws, size_t ws_size,
                              hipStream_t stream) {
  const float* x  = (const float*)d_in[0];
  const float* k  = (const float*)d_in[1];
  const float* rk = (const float*)d_in[2];
  const float* bi = (const float*)d_in[3];
  const float* dw = (const float*)d_in[4];
  const float* db = (const float*)d_in[5];
  float* ws = (float*)d_ws;
  float* out = (float*)d_out;

  hipLaunchKernelGGL(init_acc, dim3(1), dim3(64), 0, stream, ws);
  hipLaunchKernelGGL(convlstm_scan, dim3(512), dim3(256), 0, stream,
                     x, k, rk, bi, dw, ws);
  hipLaunchKernelGGL(finalize, dim3(1), dim3(64), 0, stream, ws, db, out);
}

// Round 5
// 259.477 us; speedup vs baseline: 2.1981x; 1.0269x over previous
//
#include <hip/hip_runtime.h>

// ConvLSTM1D fused scan for MI355X — f32 I/O, split-precision bf16 MFMA.
// Round 5: VALU diet. z = (Ah + Al)*Wh + xh*kh + bias  (bias folded into B
// k-row 16 with a 1.0 marker in ax; acc C = loop-invariant zero4 -> no movs).
// Halo-tile trick: block owns j-range [j0, j0+64); recurrent conv reads h[j+1]
// only, so a right halo that starts at +49 rows and shrinks by 1 per step makes
// every block's 50-step scan fully independent (no grid sync).

#define TT 50
#define LTILE 64
#define ROWS 129   // 64 owned + 49 halo + 1 read-halo row (row 128 stays 0)
#define HSTR 40    // h row stride (shorts); mult of 8 -> 16B-aligned ds_read_b128

typedef __attribute__((ext_vector_type(8))) short short8;
typedef __attribute__((ext_vector_type(4))) float floatx4;

__device__ __forceinline__ float b2f_hi(unsigned short s) {
  union { float f; unsigned u; } v; v.u = ((unsigned)s) << 16; return v.f;
}
__device__ __forceinline__ unsigned short f2b_rne(float f) {
  union { float f; unsigned u; } v; v.f = f;
  unsigned r = v.u + 0x7FFFu + ((v.u >> 16) & 1u);
  return (unsigned short)(r >> 16);
}
__device__ __forceinline__ unsigned short f2b_trunc(float f) {
  union { float f; unsigned u; } v; v.f = f;
  return (unsigned short)(v.u >> 16);
}
__device__ __forceinline__ float hsig(float x) {
  return __builtin_amdgcn_fmed3f(__builtin_fmaf(0.2f, x, 0.5f), 0.0f, 1.0f);
}
__device__ __forceinline__ float ftanh(float x) {
  float e = __expf(2.0f * x);
  return 1.0f - 2.0f * __builtin_amdgcn_rcpf(e + 1.0f);
}

__global__ __launch_bounds__(256, 2)
void convlstm_scan(const float* __restrict__ xs,   // x [32][50][2048][8] f32
                   const float* __restrict__ ks,   // kernel [2][8][128] f32
                   const float* __restrict__ rks,  // rec_kernel [2][32][128] f32
                   const float* __restrict__ bs,   // bias [128] f32
                   const float* __restrict__ dws,  // dense_w [32768] f32
                   float* __restrict__ acc_out) {  // [32] f32 accumulators
  __shared__ short hbH[2][ROWS * HSTR];   // h hi (bf16), double-buffered
  __shared__ short hbL[2][ROWS * HSTR];   // h lo (bf16)

  const int tid  = threadIdx.x;
  const int b    = blockIdx.x >> 4;
  const int j0   = (blockIdx.x & 15) * LTILE;
  const int wave = tid >> 6;
  const int lane = tid & 63;
  const int q    = lane >> 4;
  const int f0   = lane & 15;

  for (int e = tid; e < ROWS * HSTR; e += 256) {
    ((int*)hbH)[e] = 0;
    ((int*)hbL)[e] = 0;
  }

  // ---- B fragments gathered straight into registers (96 VGPR total).
  // B[k = q*8+j][oc-col = n*16+f0] per lane. rec_kernel[k][oc], k = tap*32+c.
  short8 Bwh0[8], Bwh1[8], Bxw[8];
#pragma unroll
  for (int n = 0; n < 8; ++n) {
    const int oc = n * 16 + f0;
    short8 th;
#pragma unroll
    for (int j = 0; j < 8; ++j)
      th[j] = (short)f2b_rne(rks[(q * 8 + j) * 128 + oc]);
    Bwh0[n] = th;
#pragma unroll
    for (int j = 0; j < 8; ++j)
      th[j] = (short)f2b_rne(rks[(32 + q * 8 + j) * 128 + oc]);
    Bwh1[n] = th;
    // x-conv B: k rows 0..7 = tap0 k_hi, 8..15 = tap1 k_hi (paired with x_hi),
    // row 16 = bias (ax carries 1.0 there), rows 17..31 = 0.
    short8 tx = {0, 0, 0, 0, 0, 0, 0, 0};
    if (q < 2) {
#pragma unroll
      for (int j = 0; j < 8; ++j)
        tx[j] = (short)f2b_rne(ks[(q * 8 + j) * 128 + oc]);
    } else if (q == 2) {
      tx[0] = (short)f2b_rne(bs[oc]);
    }
    Bxw[n] = tx;
  }

  // ax constant part: lane (q=2, elem 0) = bf16 1.0 (bias marker), else 0.
  short8 axc = {0, 0, 0, 0, 0, 0, 0, 0};
  if (q == 2) axc[0] = (short)0x3F80;

  const floatx4 zero4 = {0.0f, 0.0f, 0.0f, 0.0f};

  float cst[2][8];   // c-state, MFMA C-layout: [m-slot][p*4 + r]
#pragma unroll
  for (int s = 0; s < 2; ++s)
#pragma unroll
    for (int i = 0; i < 8; ++i) cst[s][i] = 0.0f;

  // ---- initial x prefetch (t=0) for both slots
  floatx4 px0[2], px1[2];
#pragma unroll
  for (int s = 0; s < 2; ++s) {
    const int jr = (wave + 4 * s) * 16 + f0;
    const int jm = min(j0 + jr, 1023);
    const float* xp = xs + (size_t)b * TT * (2048 * 8) +
                      (size_t)(2 * jm + (q & 1)) * 8;
    px0[s] = *(const floatx4*)xp;
    px1[s] = *(const floatx4*)(xp + 4);
  }

  const int maxrows = 1024 - j0;
  __syncthreads();

  for (int t = 0; t < TT; ++t) {
    const short* curH = hbH[t & 1];
    const short* curL = hbL[t & 1];
    short* nxtH = hbH[(t & 1) ^ 1];
    short* nxtL = hbL[(t & 1) ^ 1];
    int rows = LTILE + (TT - 1) - t;          // halo shrinks 1/step
    if (rows > maxrows) rows = maxrows;
    const int nmt = (rows + 15) >> 4;         // 4..8; slot0 (m=wave) always live
    const int act1 = (wave + 4) < nmt;        // wave-uniform slot1 guard
    const int tn = (t < TT - 1) ? t + 1 : t;
    const float* xnext = xs + ((size_t)(b * TT + tn)) * (2048 * 8);

    // 1) Front-load ALL a-frag LDS reads (both slots; always in-bounds:
    //    max row read = 7*16+15+1 = 128 = ROWS-1).
    short8 a0h[2], a0l[2], a1h[2], a1l[2];
#pragma unroll
    for (int s = 0; s < 2; ++s) {
      const int jr = (wave + 4 * s) * 16 + f0;
      a0h[s] = *(const short8*)&curH[jr * HSTR + q * 8];
      a0l[s] = *(const short8*)&curL[jr * HSTR + q * 8];
      a1h[s] = *(const short8*)&curH[(jr + 1) * HSTR + q * 8];
      a1l[s] = *(const short8*)&curL[(jr + 1) * HSTR + q * 8];
    }

    // 2) Build ax (x_hi only) from registers prefetched last step.
    // k = q*8+j: q0 -> hi(x[2J][j]), q1 -> hi(x[2J+1][j]), q2 -> bias marker.
    short8 ax[2];
#pragma unroll
    for (int s = 0; s < 2; ++s) {
      ax[s] = axc;
      if (q < 2) {
        floatx4 x0 = px0[s], x1 = px1[s];
#pragma unroll
        for (int jj = 0; jj < 4; ++jj) ax[s][jj] = (short)f2b_trunc(x0[jj]);
#pragma unroll
        for (int jj = 0; jj < 4; ++jj) ax[s][4 + jj] = (short)f2b_trunc(x1[jj]);
      }
    }

    // 3) Issue next-step x prefetch (longest latency, overlaps MFMA below).
#pragma unroll
    for (int s = 0; s < 2; ++s) {
      const int jr = (wave + 4 * s) * 16 + f0;
      const int jm = min(j0 + jr, 1023);
      const float* xp = xnext + (size_t)(2 * jm + (q & 1)) * 8;
      px0[s] = *(const floatx4*)xp;
      px1[s] = *(const floatx4*)(xp + 4);
    }

    // 4) Per-slot MFMA + pointwise.
#pragma unroll
    for (int s = 0; s < 2; ++s) {
      if (s == 1 && !act1) continue;
      const int m = wave + 4 * s;

      floatx4 acc[8];
      // ax first: operands in registers, C = zero4 (no acc-init movs);
      // issues while the ds_reads above are still landing.
#pragma unroll
      for (int n = 0; n < 8; ++n)
        acc[n] = __builtin_amdgcn_mfma_f32_16x16x32_bf16(ax[s], Bxw[n], zero4, 0, 0, 0);
#pragma unroll
      for (int n = 0; n < 8; ++n)
        acc[n] = __builtin_amdgcn_mfma_f32_16x16x32_bf16(a0h[s], Bwh0[n], acc[n], 0, 0, 0);
#pragma unroll
      for (int n = 0; n < 8; ++n)
        acc[n] = __builtin_amdgcn_mfma_f32_16x16x32_bf16(a1h[s], Bwh1[n], acc[n], 0, 0, 0);
#pragma unroll
      for (int n = 0; n < 8; ++n)
        acc[n] = __builtin_amdgcn_mfma_f32_16x16x32_bf16(a0l[s], Bwh0[n], acc[n], 0, 0, 0);
#pragma unroll
      for (int n = 0; n < 8; ++n)
        acc[n] = __builtin_amdgcn_mfma_f32_16x16x32_bf16(a1l[s], Bwh1[n], acc[n], 0, 0, 0);

      // Pointwise LSTM. D[m-row = q*4+r][oc-col = n*16+f0].
      // Gates: oc 0..31 = i, 32..63 = f, 64..95 = c, 96..127 = o.
      const int jw = m * 16 + q * 4;
#pragma unroll
      for (int p = 0; p < 2; ++p) {
#pragma unroll
        for (int r = 0; r < 4; ++r) {
          float zi = acc[0 + p][r], zf = acc[2 + p][r];
          float zc = acc[4 + p][r], zo = acc[6 + p][r];
          float ig = hsig(zi), fg = hsig(zf), og = hsig(zo);
          float cs = cst[s][p * 4 + r];
          float cn = __builtin_fmaf(fg, cs, ig * ftanh(zc));
          cst[s][p * 4 + r] = cn;
          float hv = og * ftanh(cn);
          // split: hi = trunc16(hv), lo = trunc16(hv - hi)  (lo rel ~2^-17)
          union { float f; unsigned u; } v; v.f = hv;
          unsigned hiu = v.u & 0xFFFF0000u;
          union { float f; unsigned u; } w; w.u = hiu;
          float rem = hv - w.f;
          nxtH[(jw + r) * HSTR + p * 16 + f0] = (short)(hiu >> 16);
          nxtL[(jw + r) * HSTR + p * 16 + f0] = (short)f2b_trunc(rem);
        }
      }
    }
    __syncthreads();
  }

  // ---- Dense(1) epilogue: final h in buffer 0 (TT even).
  const short* hH = hbH[0];
  const short* hL = hbL[0];
  float part = 0.0f;
  for (int e = tid; e < LTILE * 32; e += 256) {
    int jr = e >> 5, f = e & 31;
    float hv = b2f_hi((unsigned short)hH[jr * HSTR + f]) +
               b2f_hi((unsigned short)hL[jr * HSTR + f]);
    part += hv * dws[(j0 + jr) * 32 + f];
  }
#pragma unroll
  for (int off = 32; off > 0; off >>= 1) part += __shfl_down(part, off);
  if (lane == 0) atomicAdd(&acc_out[b], part);
}

__global__ void init_acc(float* ws) {
  if (threadIdx.x < 32) ws[threadIdx.x] = 0.0f;
}

__global__ void finalize(const float* __restrict__ ws,
                         const float* __restrict__ db,
                         float* __restrict__ out) {
  int i = threadIdx.x;
  if (i < 32) out[i] = ws[i] + db[0];
}

extern "C" void kernel_launch(void* const* d_in, const int* in_sizes, int n_in,
                              void* d_out, int out_size, void* d_ws, size_t ws_size,
                              hipStream_t stream) {
  const float* x  = (const float*)d_in[0];
  const float* k  = (const float*)d_in[1];
  const float* rk = (const float*)d_in[2];
  const float* bi = (const float*)d_in[3];
  const float* dw = (const float*)d_in[4];
  const float* db = (const float*)d_in[5];
  float* ws = (float*)d_ws;
  float* out = (float*)d_out;

  hipLaunchKernelGGL(init_acc, dim3(1), dim3(64), 0, stream, ws);
  hipLaunchKernelGGL(convlstm_scan, dim3(512), dim3(256), 0, stream,
                     x, k, rk, bi, dw, ws);
  hipLaunchKernelGGL(finalize, dim3(1), dim3(64), 0, stream, ws, db, out);
}

// Round 6
// 241.024 us; speedup vs baseline: 2.3663x; 1.0766x over previous
//
#include <hip/hip_runtime.h>

// ConvLSTM1D fused scan for MI355X — f32 I/O, bf16 MFMA.
// Round 6: h stored as rne-bf16 only (no lo plane) -> 24 MFMA/slot;
// gate-pair B permutation so each lane writes adjacent h-cols (packed b32
// store); Dense(1) fused into the t=49 pointwise (no epilogue LDS pass).
// Halo-tile trick: block owns j-range [j0, j0+64); recurrent conv reads h[j+1]
// only, so a right halo that starts at +49 rows and shrinks by 1 per step makes
// every block's 50-step scan fully independent (no grid sync).

#define TT 50
#define LTILE 64
#define ROWS 129   // 64 owned + 49 halo + 1 read-halo row (row 128 stays 0)
#define HSTR 40    // h row stride (shorts); mult of 8 -> 16B-aligned ds_read_b128

typedef __attribute__((ext_vector_type(8))) short short8;
typedef __attribute__((ext_vector_type(4))) float floatx4;

__device__ __forceinline__ unsigned short f2b_rne(float f) {
  union { float f; unsigned u; } v; v.f = f;
  unsigned r = v.u + 0x7FFFu + ((v.u >> 16) & 1u);
  return (unsigned short)(r >> 16);
}
__device__ __forceinline__ unsigned short f2b_trunc(float f) {
  union { float f; unsigned u; } v; v.f = f;
  return (unsigned short)(v.u >> 16);
}
__device__ __forceinline__ float hsig(float x) {
  return __builtin_amdgcn_fmed3f(__builtin_fmaf(0.2f, x, 0.5f), 0.0f, 1.0f);
}
__device__ __forceinline__ float ftanh(float x) {
  float e = __expf(2.0f * x);
  return 1.0f - 2.0f * __builtin_amdgcn_rcpf(e + 1.0f);
}

__global__ __launch_bounds__(256, 2)
void convlstm_scan(const float* __restrict__ xs,   // x [32][50][2048][8] f32
                   const float* __restrict__ ks,   // kernel [2][8][128] f32
                   const float* __restrict__ rks,  // rec_kernel [2][32][128] f32
                   const float* __restrict__ bs,   // bias [128] f32
                   const float* __restrict__ dws,  // dense_w [32768] f32
                   float* __restrict__ acc_out) {  // [32] f32 accumulators
  __shared__ short hbH[2][ROWS * HSTR];   // h (bf16), double-buffered

  const int tid  = threadIdx.x;
  const int b    = blockIdx.x >> 4;
  const int j0   = (blockIdx.x & 15) * LTILE;
  const int wave = tid >> 6;
  const int lane = tid & 63;
  const int q    = lane >> 4;
  const int f0   = lane & 15;

  for (int e = tid; e < ROWS * HSTR; e += 256)
    ((int*)hbH)[e] = 0;

  // ---- B fragments in registers, GATE-PAIR PERMUTED columns:
  // tile n = 2g+p, col f0  <->  oc = g*32 + 2*f0 + p   (g = gate, p = pair)
  // => lane f0's two outputs per row are adjacent h-cols 2f0, 2f0+1.
  // B[k = q*8+j][tile n, col f0] = W[k][oc]; rec_kernel[k][oc], k = tap*32+c.
  short8 Bwh0[8], Bwh1[8], Bxw[8];
#pragma unroll
  for (int n = 0; n < 8; ++n) {
    const int oc = (n >> 1) * 32 + 2 * f0 + (n & 1);
    short8 th;
#pragma unroll
    for (int j = 0; j < 8; ++j)
      th[j] = (short)f2b_rne(rks[(q * 8 + j) * 128 + oc]);
    Bwh0[n] = th;
#pragma unroll
    for (int j = 0; j < 8; ++j)
      th[j] = (short)f2b_rne(rks[(32 + q * 8 + j) * 128 + oc]);
    Bwh1[n] = th;
    // x-conv B: k rows 0..7 = tap0 k_hi, 8..15 = tap1 k_hi (paired with x_hi),
    // row 16 = bias (ax carries 1.0 there), rows 17..31 = 0.
    short8 tx = {0, 0, 0, 0, 0, 0, 0, 0};
    if (q < 2) {
#pragma unroll
      for (int j = 0; j < 8; ++j)
        tx[j] = (short)f2b_rne(ks[(q * 8 + j) * 128 + oc]);
    } else if (q == 2) {
      tx[0] = (short)f2b_rne(bs[oc]);
    }
    Bxw[n] = tx;
  }

  // ax constant part: lane (q=2, elem 0) = bf16 1.0 (bias marker), else 0.
  short8 axc = {0, 0, 0, 0, 0, 0, 0, 0};
  if (q == 2) axc[0] = (short)0x3F80;

  const floatx4 zero4 = {0.0f, 0.0f, 0.0f, 0.0f};

  float cst[2][8];   // c-state, MFMA C-layout: [m-slot][p*4 + r]
#pragma unroll
  for (int s = 0; s < 2; ++s)
#pragma unroll
    for (int i = 0; i < 8; ++i) cst[s][i] = 0.0f;

  // ---- initial x prefetch (t=0) for both slots
  floatx4 px0[2], px1[2];
#pragma unroll
  for (int s = 0; s < 2; ++s) {
    const int jr = (wave + 4 * s) * 16 + f0;
    const int jm = min(j0 + jr, 1023);
    const float* xp = xs + (size_t)b * TT * (2048 * 8) +
                      (size_t)(2 * jm + (q & 1)) * 8;
    px0[s] = *(const floatx4*)xp;
    px1[s] = *(const floatx4*)(xp + 4);
  }

  const int maxrows = 1024 - j0;
  float part = 0.0f;                        // fused Dense(1) partial
  __syncthreads();

  for (int t = 0; t < TT; ++t) {
    const short* curH = hbH[t & 1];
    short* nxtH = hbH[(t & 1) ^ 1];
    int rows = LTILE + (TT - 1) - t;          // halo shrinks 1/step
    if (rows > maxrows) rows = maxrows;
    const int nmt = (rows + 15) >> 4;         // 4..8; slot0 (m=wave) always live
    const int act1 = (wave + 4) < nmt;        // wave-uniform slot1 guard
    const int last = (t == TT - 1);
    const int tn = last ? t : t + 1;
    const float* xnext = xs + ((size_t)(b * TT + tn)) * (2048 * 8);

    // 1) Front-load a-frag LDS reads (both slots; max row read = 128 = ROWS-1).
    short8 a0h[2], a1h[2];
#pragma unroll
    for (int s = 0; s < 2; ++s) {
      const int jr = (wave + 4 * s) * 16 + f0;
      a0h[s] = *(const short8*)&curH[jr * HSTR + q * 8];
      a1h[s] = *(const short8*)&curH[(jr + 1) * HSTR + q * 8];
    }

    // 2) Build ax (x_hi) from registers prefetched last step.
    // k = q*8+j: q0 -> hi(x[2J][j]), q1 -> hi(x[2J+1][j]), q2 -> bias marker.
    short8 ax[2];
#pragma unroll
    for (int s = 0; s < 2; ++s) {
      ax[s] = axc;
      if (q < 2) {
        floatx4 x0 = px0[s], x1 = px1[s];
#pragma unroll
        for (int jj = 0; jj < 4; ++jj) ax[s][jj] = (short)f2b_trunc(x0[jj]);
#pragma unroll
        for (int jj = 0; jj < 4; ++jj) ax[s][4 + jj] = (short)f2b_trunc(x1[jj]);
      }
    }

    // 3) Issue next-step x prefetch (longest latency, overlaps MFMA below).
#pragma unroll
    for (int s = 0; s < 2; ++s) {
      const int jr = (wave + 4 * s) * 16 + f0;
      const int jm = min(j0 + jr, 1023);
      const float* xp = xnext + (size_t)(2 * jm + (q & 1)) * 8;
      px0[s] = *(const floatx4*)xp;
      px1[s] = *(const floatx4*)(xp + 4);
    }

    // 4) Per-slot MFMA + pointwise.
#pragma unroll
    for (int s = 0; s < 2; ++s) {
      if (s == 1 && !act1) continue;
      const int m = wave + 4 * s;

      floatx4 acc[8];
      // ax first: operands in registers, C = zero4; issues while ds_reads land.
#pragma unroll
      for (int n = 0; n < 8; ++n)
        acc[n] = __builtin_amdgcn_mfma_f32_16x16x32_bf16(ax[s], Bxw[n], zero4, 0, 0, 0);
#pragma unroll
      for (int n = 0; n < 8; ++n)
        acc[n] = __builtin_amdgcn_mfma_f32_16x16x32_bf16(a0h[s], Bwh0[n], acc[n], 0, 0, 0);
#pragma unroll
      for (int n = 0; n < 8; ++n)
        acc[n] = __builtin_amdgcn_mfma_f32_16x16x32_bf16(a1h[s], Bwh1[n], acc[n], 0, 0, 0);

      // Pointwise LSTM. D[m-row = q*4+r][tile n, col f0 -> h-col 2f0 + (n&1)].
      // Gate g in tiles {2g, 2g+1}: zi=acc[0+p], zf=acc[2+p], zc=acc[4+p],
      // zo=acc[6+p] give h-col 2f0+p.
      const int jw = m * 16 + q * 4;
#pragma unroll
      for (int r = 0; r < 4; ++r) {
        float hv2[2];
#pragma unroll
        for (int p = 0; p < 2; ++p) {
          float zi = acc[0 + p][r], zf = acc[2 + p][r];
          float zc = acc[4 + p][r], zo = acc[6 + p][r];
          float ig = hsig(zi), fg = hsig(zf), og = hsig(zo);
          float cs = cst[s][p * 4 + r];
          float cn = __builtin_fmaf(fg, cs, ig * ftanh(zc));
          cst[s][p * 4 + r] = cn;
          hv2[p] = og * ftanh(cn);
        }
        if (!last) {
          unsigned pk = (unsigned)f2b_rne(hv2[0]) |
                        ((unsigned)f2b_rne(hv2[1]) << 16);
          *(unsigned*)&nxtH[(jw + r) * HSTR + 2 * f0] = pk;
        } else {
          // t=49: nmt=4, s=0 only; rows jw+r cover exactly [0,64).
          const int di = (j0 + jw + r) * 32 + 2 * f0;
          part = __builtin_fmaf(hv2[0], dws[di],
                 __builtin_fmaf(hv2[1], dws[di + 1], part));
        }
      }
    }
    __syncthreads();
  }

  // ---- reduce fused-dense partials
#pragma unroll
  for (int off = 32; off > 0; off >>= 1) part += __shfl_down(part, off);
  if (lane == 0) atomicAdd(&acc_out[b], part);
}

__global__ void init_acc(float* ws) {
  if (threadIdx.x < 32) ws[threadIdx.x] = 0.0f;
}

__global__ void finalize(const float* __restrict__ ws,
                         const float* __restrict__ db,
                         float* __restrict__ out) {
  int i = threadIdx.x;
  if (i < 32) out[i] = ws[i] + db[0];
}

extern "C" void kernel_launch(void* const* d_in, const int* in_sizes, int n_in,
                              void* d_out, int out_size, void* d_ws, size_t ws_size,
                              hipStream_t stream) {
  const float* x  = (const float*)d_in[0];
  const float* k  = (const float*)d_in[1];
  const float* rk = (const float*)d_in[2];
  const float* bi = (const float*)d_in[3];
  const float* dw = (const float*)d_in[4];
  const float* db = (const float*)d_in[5];
  float* ws = (float*)d_ws;
  float* out = (float*)d_out;

  hipLaunchKernelGGL(init_acc, dim3(1), dim3(64), 0, stream, ws);
  hipLaunchKernelGGL(convlstm_scan, dim3(512), dim3(256), 0, stream,
                     x, k, rk, bi, dw, ws);
  hipLaunchKernelGGL(finalize, dim3(1), dim3(64), 0, stream, ws, db, out);
}